// Round 2
// 165.685 us; speedup vs baseline: 1.1638x; 1.1638x over previous
//
#include <hip/hip_runtime.h>
#include <math.h>

#define Bc 16
#define Nc 1024
#define Fc 256
#define Hc 8
#define Kc 512
#define DOUTc 256
#define EPSc 1e-8f

typedef short v8s __attribute__((ext_vector_type(8)));
typedef float v4f __attribute__((ext_vector_type(4)));

__device__ __forceinline__ float waveReduceSum(float v) {
    v += __shfl_xor(v, 32); v += __shfl_xor(v, 16); v += __shfl_xor(v, 8);
    v += __shfl_xor(v, 4);  v += __shfl_xor(v, 2);  v += __shfl_xor(v, 1);
    return v;
}

__device__ __forceinline__ unsigned short f2bf(float f) {
    unsigned int u = __float_as_uint(f);
    u = (u + 0x7fffu + ((u >> 16) & 1u)) >> 16;   // RNE
    return (unsigned short)u;
}

// CK-style LDS-only barrier: drains lgkmcnt but leaves global loads in flight.
__device__ __forceinline__ void lds_barrier() {
    __builtin_amdgcn_s_waitcnt(0xC07F);   // lgkmcnt(0), vmcnt=63 (no wait), expcnt=7
    __builtin_amdgcn_s_barrier();
}

// ================= fused preprocessing =================
// ranges: [0,1024)    k2 row sums        (4 key rows/block)
//         [1024,1536) kpack -> Kp        (B-frag order for cmfma)
//         [1536,3584) qpack -> Qbp       (B-frag order for vmfma)
//         [3584,3616) wpack -> Wp        (B-frag order for ofma)
//         [3616,3618) zero cn + kl
__global__ __launch_bounds__(256) void prep_all(
    const float* __restrict__ Q, const float* __restrict__ keys,
    const float* __restrict__ lin_w,
    float* __restrict__ k2g, unsigned short* __restrict__ Kp,
    unsigned short* __restrict__ Qbp, unsigned short* __restrict__ Wp,
    float* __restrict__ cn, float* __restrict__ klout) {
    __shared__ unsigned short T2[32][66];
    const int bx = blockIdx.x;
    const int tid = threadIdx.x;
    if (bx < 1024) {
        int row = bx * 4 + (tid >> 6);
        int l = tid & 63;
        float4 v = *(const float4*)(keys + (size_t)row * Fc + l * 4);
        float s = v.x * v.x + v.y * v.y + v.z * v.z + v.w * v.w;
        s = waveReduceSum(s);
        if (l == 0) k2g[row] = s;
    } else if (bx < 1536) {
        int t = (bx - 1024) * 256 + tid;
        int lane = t & 63, ci = t >> 6;
        int ct = ci & 7, ks = (ci >> 3) & 7, wv = (ci >> 6) & 3, h = ci >> 8;
        int qd = lane >> 4, li = lane & 15;
        int col = h * 512 + wv * 128 + ct * 16 + li;
        const float* src = keys + (size_t)col * Fc + ks * 32 + qd * 8;
        float4 a = *(const float4*)src;
        float4 b = *(const float4*)(src + 4);
        *(ushort4*)(Kp + (size_t)t * 8) = make_ushort4(f2bf(a.x), f2bf(a.y), f2bf(a.z), f2bf(a.w));
        *(ushort4*)(Kp + (size_t)t * 8 + 4) = make_ushort4(f2bf(b.x), f2bf(b.y), f2bf(b.z), f2bf(b.w));
    } else if (bx < 3584) {
        int i = bx - 1536;
        int n0 = (i & 31) * 32, f0 = ((i >> 5) & 3) * 64, bb = i >> 7;
        {
            int n_l = tid >> 3, f_l = (tid & 7) * 8;
            const float* src = Q + ((size_t)(bb * Nc + n0 + n_l)) * Fc + f0 + f_l;
            float4 a = *(const float4*)src;
            float4 b = *(const float4*)(src + 4);
            T2[n_l][f_l + 0] = f2bf(a.x); T2[n_l][f_l + 1] = f2bf(a.y);
            T2[n_l][f_l + 2] = f2bf(a.z); T2[n_l][f_l + 3] = f2bf(a.w);
            T2[n_l][f_l + 4] = f2bf(b.x); T2[n_l][f_l + 5] = f2bf(b.y);
            T2[n_l][f_l + 6] = f2bf(b.z); T2[n_l][f_l + 7] = f2bf(b.w);
        }
        __syncthreads();
        int c = tid >> 6, L = tid & 63;
        int qd = L >> 4, li = L & 15;
        unsigned short o[8];
#pragma unroll
        for (int j = 0; j < 8; j++) o[j] = T2[qd * 8 + j][c * 16 + li];
        size_t idx = ((((size_t)bb * 16 + (f0 >> 4) + c) * 32 + (n0 >> 5)) * 64 + L) * 8;
        *(ushort4*)(Qbp + idx) = make_ushort4(o[0], o[1], o[2], o[3]);
        *(ushort4*)(Qbp + idx + 4) = make_ushort4(o[4], o[5], o[6], o[7]);
    } else if (bx < 3616) {
        int t = (bx - 3584) * 256 + tid;
        int lane = t & 63, ci = t >> 6;
        int ot = ci >> 3, fs = ci & 7;
        int qd = lane >> 4, li = lane & 15;
        const float* src = lin_w + (size_t)(ot * 16 + li) * Fc + fs * 32 + qd * 8;
        float4 a = *(const float4*)src;
        float4 b = *(const float4*)(src + 4);
        *(ushort4*)(Wp + (size_t)t * 8) = make_ushort4(f2bf(a.x), f2bf(a.y), f2bf(a.z), f2bf(a.w));
        *(ushort4*)(Wp + (size_t)t * 8 + 4) = make_ushort4(f2bf(b.x), f2bf(b.y), f2bf(b.z), f2bf(b.w));
    } else {
        int i = (bx - 3616) * 256 + tid;   // 512 threads x 16 floats = 8192
        float4 z = make_float4(0.f, 0.f, 0.f, 0.f);
        float4* d = (float4*)(cn + (size_t)i * 16);
        d[0] = z; d[1] = z; d[2] = z; d[3] = z;
        if (bx == 3616 && tid == 0) *klout = 0.f;
    }
}

// ====== fused distance-GEMM (32 rows/block) with light barriers ======
// A-fragments are identical across the 4 waves -> build once into LDS
// (union'd with the epilogue-only Tb transpose buffer), prefetch one kk
// ahead into 2 rotating v8s regs. Frees ~48 unified regs -> 2 waves/SIMD.
__global__ __launch_bounds__(256, 2) void cmfma_kernel(
    const float* __restrict__ Q, const unsigned short* __restrict__ Kp,
    const float* __restrict__ k2g, const float* __restrict__ conv_w,
    const int* __restrict__ mask, float* __restrict__ C,
    float* __restrict__ cn, unsigned short* __restrict__ Ctp) {
    // union: main phase = k2s (16KB) + Ash (16KB); epilogue = Tb (36.9KB)
    __shared__ __align__(16) char uni[36864];
    __shared__ float q2h[4][16];
    __shared__ float msh[32];
    __shared__ float redb[Hc][4][32];       // 4 KB, dedicated slot per head
    __shared__ float mslot[4][32];
    __shared__ float eslot[4][32];
    float* k2s = (float*)uni;               // [0, 16384)
    short* Ash = (short*)(uni + 16384);     // [16384, 32768)  16 frags x 64 lanes x 16B
    short (*Tb)[36] = (short (*)[36])uni;   // epilogue only (2 barriers after last Ash/k2s read)

    const int tid = threadIdx.x;
    const int wv = tid >> 6, L = tid & 63;
    const int qd = L >> 4, li = L & 15;
    const int gr0 = blockIdx.x * 32;
    const int b = gr0 >> 10;

    // ---- cooperative A-frag build: wave wv builds frags fi = wv*4..wv*4+3 ----
    // fi = s*8+ks ; lane (qd,li) holds Q[gr0+s*16+li][ks*32+qd*8 .. +8] as bf16
    {
        int s_ = wv >> 1;
        int ksbase = (wv & 1) * 4;
        const float* qrow = Q + (size_t)(gr0 + s_ * 16 + li) * Fc + qd * 8;
        float q2part = 0.f;
#pragma unroll
        for (int j = 0; j < 4; j++) {
            int ks = ksbase + j;
            float4 a = *(const float4*)(qrow + ks * 32);
            float4 bq = *(const float4*)(qrow + ks * 32 + 4);
            v8s f;
            f[0] = (short)f2bf(a.x);  f[1] = (short)f2bf(a.y);
            f[2] = (short)f2bf(a.z);  f[3] = (short)f2bf(a.w);
            f[4] = (short)f2bf(bq.x); f[5] = (short)f2bf(bq.y);
            f[6] = (short)f2bf(bq.z); f[7] = (short)f2bf(bq.w);
            *(v8s*)&Ash[(((s_ * 8 + ks) * 64) + L) * 8] = f;
            q2part += a.x * a.x + a.y * a.y + a.z * a.z + a.w * a.w +
                      bq.x * bq.x + bq.y * bq.y + bq.z * bq.z + bq.w * bq.w;
        }
        // reduce across qd (4 chunks within this wave); rows split across 2 waves/s
        q2part += __shfl_xor(q2part, 16);
        q2part += __shfl_xor(q2part, 32);
        if (qd == 0) q2h[wv][li] = q2part;
    }
    if (tid < 32) msh[tid] = (float)mask[gr0 + tid];
    for (int i = tid; i < Hc * Kc / 4; i += 256)
        *(float4*)&k2s[i * 4] = *(const float4*)(k2g + i * 4);

    v4f D[2][8], S[2][8];
#pragma unroll
    for (int s = 0; s < 2; s++)
#pragma unroll
        for (int ct = 0; ct < 8; ct++) {
            D[s][ct] = (v4f){0.f, 0.f, 0.f, 0.f};
            S[s][ct] = (v4f){0.f, 0.f, 0.f, 0.f};
        }

    const unsigned short* kwbase = Kp + (size_t)L * 8;
    v8s Bc0[8], Bn[8];
    {
        const unsigned short* p0 = kwbase + (size_t)(wv * 64) * 512;
#pragma unroll
        for (int ct = 0; ct < 8; ct++) Bc0[ct] = *(const v8s*)(p0 + ct * 512);
    }

    lds_barrier();   // q2h/msh/k2s/Ash visible; global loads stay in flight

    float q2r[2][4], mrow[2][4];
#pragma unroll
    for (int s = 0; s < 2; s++)
#pragma unroll
        for (int r = 0; r < 4; r++) {
            q2r[s][r] = q2h[2 * s][qd * 4 + r] + q2h[2 * s + 1][qd * 4 + r];
            mrow[s][r] = msh[s * 16 + qd * 4 + r];
        }

#define LD_A(s, kk) (*(const v8s*)&Ash[(((s) * 8 + (kk)) * 64 + L) * 8])

    v8s Ac0 = LD_A(0, 0);
    v8s Ac1 = LD_A(1, 0);

#define KSTEP(kk, CUR, NXT)                                                        \
    do {                                                                           \
        int hn = h * 8 + (kk) + 1;                                                 \
        int hh = (hn >> 3) & 7, kn = hn & 7;                                       \
        const unsigned short* pb =                                                 \
            kwbase + (size_t)(((hh * 4 + wv) * 64 + kn * 8)) * 512;                \
        _Pragma("unroll") for (int ct = 0; ct < 8; ct++)                           \
            NXT[ct] = *(const v8s*)(pb + ct * 512);                                \
        v8s An0 = LD_A(0, ((kk) + 1) & 7);                                         \
        v8s An1 = LD_A(1, ((kk) + 1) & 7);                                         \
        _Pragma("unroll") for (int ct = 0; ct < 8; ct++)                           \
            D[0][ct] = __builtin_amdgcn_mfma_f32_16x16x32_bf16(Ac0, CUR[ct],       \
                                                               D[0][ct], 0, 0, 0);\
        _Pragma("unroll") for (int ct = 0; ct < 8; ct++)                           \
            D[1][ct] = __builtin_amdgcn_mfma_f32_16x16x32_bf16(Ac1, CUR[ct],       \
                                                               D[1][ct], 0, 0, 0);\
        Ac0 = An0; Ac1 = An1;                                                      \
    } while (0)

    for (int h = 0; h < Hc; ++h) {
        KSTEP(0, Bc0, Bn); KSTEP(1, Bn, Bc0);
        KSTEP(2, Bc0, Bn); KSTEP(3, Bn, Bc0);
        KSTEP(4, Bc0, Bn); KSTEP(5, Bn, Bc0);
        KSTEP(6, Bc0, Bn); KSTEP(7, Bn, Bc0);

        float rs[2][4] = {{0.f, 0.f, 0.f, 0.f}, {0.f, 0.f, 0.f, 0.f}};
#pragma unroll
        for (int ct = 0; ct < 8; ct++) {
            float k2v = k2s[h * Kc + wv * 128 + ct * 16 + li];
#pragma unroll
            for (int s = 0; s < 2; s++)
#pragma unroll
                for (int r = 0; r < 4; r++) {
                    float d2 = fmaxf(q2r[s][r] + k2v - 2.f * D[s][ct][r], 0.f) * mrow[s][r];
                    float t = __builtin_amdgcn_rcpf(1.f + d2);
                    D[s][ct][r] = t;
                    rs[s][r] += t;
                }
        }
#pragma unroll
        for (int s = 0; s < 2; s++)
#pragma unroll
            for (int r = 0; r < 4; r++) {
                rs[s][r] += __shfl_xor(rs[s][r], 1, 16);
                rs[s][r] += __shfl_xor(rs[s][r], 2, 16);
                rs[s][r] += __shfl_xor(rs[s][r], 4, 16);
                rs[s][r] += __shfl_xor(rs[s][r], 8, 16);
            }
        if (li == 0) {
#pragma unroll
            for (int s = 0; s < 2; s++)
#pragma unroll
                for (int r = 0; r < 4; r++) redb[h][wv][s * 16 + qd * 4 + r] = rs[s][r];
        }
        lds_barrier();   // slot h never reused -> single light barrier per head
        float wh = conv_w[h];
        float sc[2][4];
#pragma unroll
        for (int s = 0; s < 2; s++)
#pragma unroll
            for (int r = 0; r < 4; r++) {
                int rw = s * 16 + qd * 4 + r;
                float tot = redb[h][0][rw] + redb[h][1][rw] + redb[h][2][rw] + redb[h][3][rw];
                sc[s][r] = wh * __builtin_amdgcn_rcpf(tot);
            }
#pragma unroll
        for (int s = 0; s < 2; s++)
#pragma unroll
            for (int ct = 0; ct < 8; ct++)
#pragma unroll
                for (int r = 0; r < 4; r++) {
                    S[s][ct][r] += sc[s][r] * D[s][ct][r];
                    D[s][ct][r] = 0.f;
                }
    }
#undef KSTEP
#undef LD_A

    // ---- softmax over 512 cols (light barriers) ----
    float mx[2][4] = {{-1e30f, -1e30f, -1e30f, -1e30f}, {-1e30f, -1e30f, -1e30f, -1e30f}};
#pragma unroll
    for (int s = 0; s < 2; s++)
#pragma unroll
        for (int ct = 0; ct < 8; ct++)
#pragma unroll
            for (int r = 0; r < 4; r++) mx[s][r] = fmaxf(mx[s][r], S[s][ct][r]);
#pragma unroll
    for (int s = 0; s < 2; s++)
#pragma unroll
        for (int r = 0; r < 4; r++) {
            mx[s][r] = fmaxf(mx[s][r], __shfl_xor(mx[s][r], 1, 16));
            mx[s][r] = fmaxf(mx[s][r], __shfl_xor(mx[s][r], 2, 16));
            mx[s][r] = fmaxf(mx[s][r], __shfl_xor(mx[s][r], 4, 16));
            mx[s][r] = fmaxf(mx[s][r], __shfl_xor(mx[s][r], 8, 16));
        }
    if (li == 0) {
#pragma unroll
        for (int s = 0; s < 2; s++)
#pragma unroll
            for (int r = 0; r < 4; r++) mslot[wv][s * 16 + qd * 4 + r] = mx[s][r];
    }
    lds_barrier();
#pragma unroll
    for (int s = 0; s < 2; s++)
#pragma unroll
        for (int r = 0; r < 4; r++) {
            int rw = s * 16 + qd * 4 + r;
            mx[s][r] = fmaxf(fmaxf(mslot[0][rw], mslot[1][rw]),
                             fmaxf(mslot[2][rw], mslot[3][rw]));
        }
    float es[2][4] = {{0.f, 0.f, 0.f, 0.f}, {0.f, 0.f, 0.f, 0.f}};
#pragma unroll
    for (int s = 0; s < 2; s++)
#pragma unroll
        for (int ct = 0; ct < 8; ct++)
#pragma unroll
            for (int r = 0; r < 4; r++) {
                float e = __expf(S[s][ct][r] - mx[s][r]);
                S[s][ct][r] = e;
                es[s][r] += e;
            }
#pragma unroll
    for (int s = 0; s < 2; s++)
#pragma unroll
        for (int r = 0; r < 4; r++) {
            es[s][r] += __shfl_xor(es[s][r], 1, 16);
            es[s][r] += __shfl_xor(es[s][r], 2, 16);
            es[s][r] += __shfl_xor(es[s][r], 4, 16);
            es[s][r] += __shfl_xor(es[s][r], 8, 16);
        }
    if (li == 0) {
#pragma unroll
        for (int s = 0; s < 2; s++)
#pragma unroll
            for (int r = 0; r < 4; r++) eslot[wv][s * 16 + qd * 4 + r] = es[s][r];
    }
    lds_barrier();
    float inv[2][4];
#pragma unroll
    for (int s = 0; s < 2; s++)
#pragma unroll
        for (int r = 0; r < 4; r++) {
            int rw = s * 16 + qd * 4 + r;
            float tot = eslot[0][rw] + eslot[1][rw] + eslot[2][rw] + eslot[3][rw];
            inv[s][r] = mrow[s][r] / tot;
        }
#pragma unroll
    for (int ct = 0; ct < 8; ct++) {
        int k = wv * 128 + ct * 16 + li;
        float colsum = 0.f;
#pragma unroll
        for (int s = 0; s < 2; s++) {
            float cv[4];
#pragma unroll
            for (int r = 0; r < 4; r++) {
                cv[r] = S[s][ct][r] * inv[s][r];
                C[(size_t)(gr0 + s * 16 + qd * 4 + r) * Kc + k] = cv[r];
                colsum += cv[r];
            }
            short4 t4;
            t4.x = (short)f2bf(cv[0]); t4.y = (short)f2bf(cv[1]);
            t4.z = (short)f2bf(cv[2]); t4.w = (short)f2bf(cv[3]);
            *(short4*)&Tb[k][s * 16 + qd * 4] = t4;
        }
        colsum += __shfl_xor(colsum, 16);
        colsum += __shfl_xor(colsum, 32);
        if (qd == 0) atomicAdd(&cn[b * Kc + k], colsum);
    }
    lds_barrier();
    {
        const int ns0 = (gr0 & 1023) >> 5;
#pragma unroll
        for (int kk = 0; kk < 2; kk++) {
            int k = tid * 2 + kk;
            int kt = k >> 4, klo = k & 15;
            size_t cbase = (((size_t)b * 32 + kt) * 32 + ns0) * 512;
#pragma unroll
            for (int q2i = 0; q2i < 4; q2i++) {
                short4 lo = *(short4*)&Tb[k][q2i * 8];
                short4 hi = *(short4*)&Tb[k][q2i * 8 + 4];
                short4* d = (short4*)(Ctp + cbase + (size_t)(q2i * 16 + klo) * 8);
                d[0] = lo; d[1] = hi;
            }
        }
    }
}

// ---- fused: [0,512) vmfma (V = C^T Q -> Vp bf16 packed); [512,1536) kl ----
__global__ __launch_bounds__(256) void klv_kernel(
    const unsigned short* __restrict__ Ctp, const unsigned short* __restrict__ Qbp,
    unsigned short* __restrict__ Vp, const float* __restrict__ C,
    const float* __restrict__ cn, float* __restrict__ klout) {
    __shared__ short Vt[64][76];
    __shared__ float red[4];
    int tid = threadIdx.x;
    int bx = blockIdx.x;
    if (bx < 512) {
        int w = tid >> 6, L = tid & 63;
        int qd = L >> 4, li = L & 15;
        int wr = w >> 1, wc = w & 1;
        int bb = bx >> 5;
        int rem = bx & 31;
        int ktb = rem >> 2, ftb = rem & 3;
        int KT0 = ktb * 4 + wr * 2;
        int FT0 = ftb * 4 + wc * 2;
        const unsigned short* pa0 = Ctp + (((size_t)bb * 32 + KT0) * 32) * 512 + L * 8;
        const unsigned short* pa1 = pa0 + (size_t)32 * 512;
        const unsigned short* pb0 = Qbp + (((size_t)bb * 16 + FT0) * 32) * 512 + L * 8;
        const unsigned short* pb1 = pb0 + (size_t)32 * 512;
        v4f acc[2][2];
#pragma unroll
        for (int a = 0; a < 2; a++)
#pragma unroll
            for (int c = 0; c < 2; c++) acc[a][c] = (v4f){0.f, 0.f, 0.f, 0.f};

        v8s A0 = *(const v8s*)pa0, A1 = *(const v8s*)pa1;
        v8s B0 = *(const v8s*)pb0, B1 = *(const v8s*)pb1;
        for (int ns = 0; ns < 32; ns++) {
            int nsn = (ns + 1) & 31;
            v8s A0n = *(const v8s*)(pa0 + nsn * 512);
            v8s A1n = *(const v8s*)(pa1 + nsn * 512);
            v8s B0n = *(const v8s*)(pb0 + nsn * 512);
            v8s B1n = *(const v8s*)(pb1 + nsn * 512);
            acc[0][0] = __builtin_amdgcn_mfma_f32_16x16x32_bf16(A0, B0, acc[0][0], 0, 0, 0);
            acc[0][1] = __builtin_amdgcn_mfma_f32_16x16x32_bf16(A0, B1, acc[0][1], 0, 0, 0);
            acc[1][0] = __builtin_amdgcn_mfma_f32_16x16x32_bf16(A1, B0, acc[1][0], 0, 0, 0);
            acc[1][1] = __builtin_amdgcn_mfma_f32_16x16x32_bf16(A1, B1, acc[1][1], 0, 0, 0);
            A0 = A0n; A1 = A1n; B0 = B0n; B1 = B1n;
        }
#pragma unroll
        for (int a = 0; a < 2; a++)
#pragma unroll
            for (int c = 0; c < 2; c++)
#pragma unroll
                for (int r = 0; r < 4; r++)
                    Vt[(wr * 2 + a) * 16 + qd * 4 + r][(wc * 2 + c) * 16 + li] =
                        (short)f2bf(acc[a][c][r]);
        __syncthreads();
        {
            int ci = tid >> 5, s5 = tid & 31;
            int mtl = ci >> 1, fsl = ci & 1;
            size_t mt_g = (size_t)bb * 32 + ktb * 4 + mtl;
            size_t fs_g = (size_t)ftb * 2 + fsl;
#pragma unroll
            for (int half = 0; half < 2; half++) {
                int L2 = s5 + half * 32;
                int qd2 = L2 >> 4, li2 = L2 & 15;
                short4 x0 = *(short4*)&Vt[mtl * 16 + li2][fsl * 32 + qd2 * 8];
                short4 x1 = *(short4*)&Vt[mtl * 16 + li2][fsl * 32 + qd2 * 8 + 4];
                short4* d = (short4*)(Vp + ((mt_g * 8 + fs_g) * 64 + L2) * 8);
                d[0] = x0; d[1] = x1;
            }
        }
    } else {
        int bk = bx - 512;
        int w = tid >> 6, l = tid & 63;
        float kacc = 0.f;
#pragma unroll
        for (int rr = 0; rr < 4; rr++) {
            int row = bk * 16 + w * 4 + rr;
            int b = row >> 10;
            const float* cp = C + (size_t)row * Kc + l * 8;
            const float* np = cn + b * Kc + l * 8;
            float4 c0 = *(const float4*)cp;
            float4 c1 = *(const float4*)(cp + 4);
            float4 n0 = *(const float4*)np;
            float4 n1 = *(const float4*)(np + 4);
            float p[8];
            p[0] = c0.x * c0.x / (n0.x + EPSc); p[1] = c0.y * c0.y / (n0.y + EPSc);
            p[2] = c0.z * c0.z / (n0.z + EPSc); p[3] = c0.w * c0.w / (n0.w + EPSc);
            p[4] = c1.x * c1.x / (n1.x + EPSc); p[5] = c1.y * c1.y / (n1.y + EPSc);
            p[6] = c1.z * c1.z / (n1.z + EPSc); p[7] = c1.w * c1.w / (n1.w + EPSc);
            float s = p[0] + p[1] + p[2] + p[3] + p[4] + p[5] + p[6] + p[7];
            float pn = waveReduceSum(s) + EPSc;
            float rpn = 1.0f / pn;
            float cc[8] = {c0.x, c0.y, c0.z, c0.w, c1.x, c1.y, c1.z, c1.w};
#pragma unroll
            for (int j = 0; j < 8; j++) {
                float P = p[j] * rpn;
                kacc += P * __logf((P + EPSc) / (cc[j] + EPSc));
            }
        }
        kacc = waveReduceSum(kacc);
        if (l == 0) red[w] = kacc;
        __syncthreads();
        if (tid == 0)
            atomicAdd(klout, 100.f * (red[0] + red[1] + red[2] + red[3]));
    }
}

// ---- out = leaky_relu(Vp @ Wp^T + b) via MFMA ----
__global__ __launch_bounds__(256) void ofma_kernel(
    const unsigned short* __restrict__ Vp, const unsigned short* __restrict__ Wp,
    const float* __restrict__ bias, float* __restrict__ out) {
    int tid = threadIdx.x;
    int w = tid >> 6, L = tid & 63;
    int qd = L >> 4, li = L & 15;
    int wr = w >> 1, wc = w & 1;
    int MT0 = blockIdx.x * 4 + wr * 2;
    int OT0 = blockIdx.y * 4 + wc * 2;
    const unsigned short* pa0 = Vp + ((size_t)MT0 * 8) * 512 + L * 8;
    const unsigned short* pa1 = pa0 + (size_t)8 * 512;
    const unsigned short* pb0 = Wp + ((size_t)OT0 * 8) * 512 + L * 8;
    const unsigned short* pb1 = pb0 + (size_t)8 * 512;
    v4f acc[2][2];
#pragma unroll
    for (int a = 0; a < 2; a++)
#pragma unroll
        for (int c = 0; c < 2; c++) acc[a][c] = (v4f){0.f, 0.f, 0.f, 0.f};
#pragma unroll
    for (int fs = 0; fs < 8; fs++) {
        v8s A0 = *(const v8s*)(pa0 + fs * 512);
        v8s A1 = *(const v8s*)(pa1 + fs * 512);
        v8s B0 = *(const v8s*)(pb0 + fs * 512);
        v8s B1 = *(const v8s*)(pb1 + fs * 512);
        acc[0][0] = __builtin_amdgcn_mfma_f32_16x16x32_bf16(A0, B0, acc[0][0], 0, 0, 0);
        acc[0][1] = __builtin_amdgcn_mfma_f32_16x16x32_bf16(A0, B1, acc[0][1], 0, 0, 0);
        acc[1][0] = __builtin_amdgcn_mfma_f32_16x16x32_bf16(A1, B0, acc[1][0], 0, 0, 0);
        acc[1][1] = __builtin_amdgcn_mfma_f32_16x16x32_bf16(A1, B1, acc[1][1], 0, 0, 0);
    }
#pragma unroll
    for (int c = 0; c < 2; c++) {
        float bv = bias[(OT0 + c) * 16 + li];
#pragma unroll
        for (int a = 0; a < 2; a++)
#pragma unroll
            for (int r = 0; r < 4; r++) {
                int m = (MT0 + a) * 16 + qd * 4 + r;
                int o = (OT0 + c) * 16 + li;
                float x = acc[a][c][r] + bv;
                out[(size_t)m * DOUTc + o] = x > 0.f ? x : 0.01f * x;
            }
    }
}

extern "C" void kernel_launch(void* const* d_in, const int* in_sizes, int n_in,
                              void* d_out, int out_size, void* d_ws, size_t ws_size,
                              hipStream_t stream) {
    const float* Q = (const float*)d_in[0];
    const float* keys = (const float*)d_in[1];
    const float* conv_w = (const float*)d_in[2];
    const float* lin_w = (const float*)d_in[3];
    const float* lin_b = (const float*)d_in[4];
    const int* mask = (const int*)d_in[5];

    float* out = (float*)d_out;
    float* kl = out + (size_t)Bc * Kc * DOUTc;

    float* ws = (float*)d_ws;
    float* C = ws;                                   // 8,388,608 f
    float* k2 = C + (size_t)Bc * Nc * Kc;            // 4,096 f
    float* cn = k2 + (size_t)Hc * Kc;                // 8,192 f
    unsigned short* Kp = (unsigned short*)(cn + (size_t)Bc * Kc);  // 1,048,576 us
    unsigned short* Ctp = Kp + (size_t)Hc * Kc * Fc;               // 8,388,608 us
    unsigned short* Qbp = Ctp + (size_t)Bc * Nc * Kc;              // 4,194,304 us
    unsigned short* Vp = Qbp + (size_t)Bc * Nc * Fc;               // 2,097,152 us
    unsigned short* Wp = Vp + (size_t)Bc * Kc * Fc;                // 65,536 us

    prep_all<<<3618, 256, 0, stream>>>(Q, keys, lin_w, k2, Kp, Qbp, Wp, cn, kl);
    cmfma_kernel<<<Bc * Nc / 32, 256, 0, stream>>>(Q, Kp, k2, conv_w, mask, C, cn, Ctp);
    klv_kernel<<<1536, 256, 0, stream>>>(Ctp, Qbp, Vp, C, cn, kl);
    ofma_kernel<<<dim3(Bc * Kc / 64, DOUTc / 64), 256, 0, stream>>>(Vp, Wp, lin_b, out);
}